// Round 1
// baseline (1100.021 us; speedup 1.0000x reference)
//
#include <hip/hip_runtime.h>

// GGNN: B=16, N=512, U=128, E=8, N_STEP=3
#define B_ 16
#define N_ 512
#define U_ 128
#define E_ 8
#define TH_ 384      // 3*U
#define BN_ 8192     // B*N
#define EU_ 1024     // E*U
#define NSTEP 3

__device__ __forceinline__ float sigm(float x) { return 1.0f / (1.0f + expf(-x)); }

// ---------------------------------------------------------------------------
// K1: edge transform  H[b][e][n][u] = sum_d state[b*N+n][d] * W[e][d][u] + bias[e][u]
// grid (U/64, BN/64, E), block 256
__global__ __launch_bounds__(256) void k_edge(const float* __restrict__ S,
                                              const float* __restrict__ W,
                                              const float* __restrict__ bias,
                                              float* __restrict__ H) {
    const int e = blockIdx.z;
    const int row0 = blockIdx.y * 64;   // over BN
    const int col0 = blockIdx.x * 64;   // over U
    const float* A = S;                  // [BN x U]
    const float* Bm = W + (size_t)e * U_ * U_;  // [U x U]
    __shared__ float As[16][68];
    __shared__ float Bs[16][68];
    const int tid = threadIdx.x;
    const int tr = tid >> 4, tc = tid & 15;
    float acc[4][4] = {};
    for (int k0 = 0; k0 < U_; k0 += 16) {
        __syncthreads();
#pragma unroll
        for (int j = 0; j < 4; ++j) {
            int f = tid + 256 * j;
            int m = f >> 4, k = f & 15;
            As[k][m] = A[(size_t)(row0 + m) * U_ + k0 + k];
            int kb = f >> 6, n = f & 63;
            Bs[kb][n] = Bm[(size_t)(k0 + kb) * U_ + col0 + n];
        }
        __syncthreads();
#pragma unroll
        for (int k = 0; k < 16; ++k) {
            float4 av = *reinterpret_cast<const float4*>(&As[k][tr * 4]);
            float4 bv = *reinterpret_cast<const float4*>(&Bs[k][tc * 4]);
            float a[4] = {av.x, av.y, av.z, av.w};
            float b[4] = {bv.x, bv.y, bv.z, bv.w};
#pragma unroll
            for (int i = 0; i < 4; ++i)
#pragma unroll
                for (int j = 0; j < 4; ++j) acc[i][j] = fmaf(a[i], b[j], acc[i][j]);
        }
    }
#pragma unroll
    for (int i = 0; i < 4; ++i) {
        int R = row0 + tr * 4 + i;
        int b = R >> 9;          // / N
        int n = R & 511;
        float* out = H + ((size_t)(b * E_ + e) * N_ + n) * U_;
#pragma unroll
        for (int j = 0; j < 4; ++j) {
            int u = col0 + tc * 4 + j;
            out[u] = acc[i][j] + bias[e * U_ + u];
        }
    }
}

// ---------------------------------------------------------------------------
// K2: neigh[b][n][e][u] = sig(alpha[e]) * sum_m adj[b][e][n][m] * H[b][e][m][u]
// grid (U/64, N/64, B*E), block 256
__global__ __launch_bounds__(256) void k_neigh(const float* __restrict__ ADJ,
                                               const float* __restrict__ H,
                                               const float* __restrict__ alpha,
                                               float* __restrict__ NG) {
    const int be = blockIdx.z;
    const int b = be >> 3, e = be & 7;
    const int row0 = blockIdx.y * 64;   // over N
    const int col0 = blockIdx.x * 64;   // over U
    const float sa = sigm(alpha[e]);
    const float* A = ADJ + (size_t)be * N_ * N_;   // [N x N]
    const float* Bm = H + (size_t)be * N_ * U_;    // [N x U]
    __shared__ float As[16][68];
    __shared__ float Bs[16][68];
    const int tid = threadIdx.x;
    const int tr = tid >> 4, tc = tid & 15;
    float acc[4][4] = {};
    for (int k0 = 0; k0 < N_; k0 += 16) {
        __syncthreads();
#pragma unroll
        for (int j = 0; j < 4; ++j) {
            int f = tid + 256 * j;
            int m = f >> 4, k = f & 15;
            As[k][m] = A[(size_t)(row0 + m) * N_ + k0 + k];
            int kb = f >> 6, n = f & 63;
            Bs[kb][n] = Bm[(size_t)(k0 + kb) * U_ + col0 + n];
        }
        __syncthreads();
#pragma unroll
        for (int k = 0; k < 16; ++k) {
            float4 av = *reinterpret_cast<const float4*>(&As[k][tr * 4]);
            float4 bv = *reinterpret_cast<const float4*>(&Bs[k][tc * 4]);
            float a[4] = {av.x, av.y, av.z, av.w};
            float b2[4] = {bv.x, bv.y, bv.z, bv.w};
#pragma unroll
            for (int i = 0; i < 4; ++i)
#pragma unroll
                for (int j = 0; j < 4; ++j) acc[i][j] = fmaf(a[i], b2[j], acc[i][j]);
        }
    }
#pragma unroll
    for (int i = 0; i < 4; ++i) {
        int n = row0 + tr * 4 + i;
        float* out = NG + ((size_t)(b * N_ + n) * E_ + e) * U_;
#pragma unroll
        for (int j = 0; j < 4; ++j) {
            int u = col0 + tc * 4 + j;
            out[u] = sa * acc[i][j];
        }
    }
}

// ---------------------------------------------------------------------------
// K3: M[8192 x 384] = NG[8192 x 1024] @ GK[1024 x 384] + gbias
// grid (384/64, BN/64), block 256
__global__ __launch_bounds__(256) void k_gruin(const float* __restrict__ NG,
                                               const float* __restrict__ GK,
                                               const float* __restrict__ gbias,
                                               float* __restrict__ M) {
    const int row0 = blockIdx.y * 64;
    const int col0 = blockIdx.x * 64;
    __shared__ float As[16][68];
    __shared__ float Bs[16][68];
    const int tid = threadIdx.x;
    const int tr = tid >> 4, tc = tid & 15;
    float acc[4][4] = {};
    for (int k0 = 0; k0 < EU_; k0 += 16) {
        __syncthreads();
#pragma unroll
        for (int j = 0; j < 4; ++j) {
            int f = tid + 256 * j;
            int m = f >> 4, k = f & 15;
            As[k][m] = NG[(size_t)(row0 + m) * EU_ + k0 + k];
            int kb = f >> 6, n = f & 63;
            Bs[kb][n] = GK[(size_t)(k0 + kb) * TH_ + col0 + n];
        }
        __syncthreads();
#pragma unroll
        for (int k = 0; k < 16; ++k) {
            float4 av = *reinterpret_cast<const float4*>(&As[k][tr * 4]);
            float4 bv = *reinterpret_cast<const float4*>(&Bs[k][tc * 4]);
            float a[4] = {av.x, av.y, av.z, av.w};
            float b2[4] = {bv.x, bv.y, bv.z, bv.w};
#pragma unroll
            for (int i = 0; i < 4; ++i)
#pragma unroll
                for (int j = 0; j < 4; ++j) acc[i][j] = fmaf(a[i], b2[j], acc[i][j]);
        }
    }
#pragma unroll
    for (int i = 0; i < 4; ++i) {
        int R = row0 + tr * 4 + i;
#pragma unroll
        for (int j = 0; j < 4; ++j) {
            int c = col0 + tc * 4 + j;
            M[(size_t)R * TH_ + c] = acc[i][j] + gbias[c];
        }
    }
}

// ---------------------------------------------------------------------------
// K4: M[:, 0:256] += state[8192 x 128] @ REC[:, 0:256]   (REC ld = 384)
// grid (256/64, BN/64), block 256
__global__ __launch_bounds__(256) void k_reczr(const float* __restrict__ S,
                                               const float* __restrict__ REC,
                                               float* __restrict__ M) {
    const int row0 = blockIdx.y * 64;
    const int col0 = blockIdx.x * 64;   // within [0,256)
    __shared__ float As[16][68];
    __shared__ float Bs[16][68];
    const int tid = threadIdx.x;
    const int tr = tid >> 4, tc = tid & 15;
    float acc[4][4] = {};
    for (int k0 = 0; k0 < U_; k0 += 16) {
        __syncthreads();
#pragma unroll
        for (int j = 0; j < 4; ++j) {
            int f = tid + 256 * j;
            int m = f >> 4, k = f & 15;
            As[k][m] = S[(size_t)(row0 + m) * U_ + k0 + k];
            int kb = f >> 6, n = f & 63;
            Bs[kb][n] = REC[(size_t)(k0 + kb) * TH_ + col0 + n];
        }
        __syncthreads();
#pragma unroll
        for (int k = 0; k < 16; ++k) {
            float4 av = *reinterpret_cast<const float4*>(&As[k][tr * 4]);
            float4 bv = *reinterpret_cast<const float4*>(&Bs[k][tc * 4]);
            float a[4] = {av.x, av.y, av.z, av.w};
            float b2[4] = {bv.x, bv.y, bv.z, bv.w};
#pragma unroll
            for (int i = 0; i < 4; ++i)
#pragma unroll
                for (int j = 0; j < 4; ++j) acc[i][j] = fmaf(a[i], b2[j], acc[i][j]);
        }
    }
#pragma unroll
    for (int i = 0; i < 4; ++i) {
        int R = row0 + tr * 4 + i;
#pragma unroll
        for (int j = 0; j < 4; ++j) {
            int c = col0 + tc * 4 + j;
            M[(size_t)R * TH_ + c] += acc[i][j];
        }
    }
}

// ---------------------------------------------------------------------------
// E1: z = sigm(M[:,0:128]); r = sigm(M[:,128:256]); M[:,0:128] = z; RH = r*state
__global__ __launch_bounds__(256) void k_gates(const float* __restrict__ S,
                                               float* __restrict__ M,
                                               float* __restrict__ RH) {
    int i = blockIdx.x * 256 + threadIdx.x;   // < BN*U
    int row = i >> 7, u = i & 127;
    float z = sigm(M[(size_t)row * TH_ + u]);
    float r = sigm(M[(size_t)row * TH_ + 128 + u]);
    M[(size_t)row * TH_ + u] = z;
    RH[i] = r * S[i];
}

// ---------------------------------------------------------------------------
// K5: hh_lin = RH @ REC[:, 256:384]; state = z*state + (1-z)*tanh(xh + hh_lin)
// grid (128/64, BN/64), block 256 — writes state in place
__global__ __launch_bounds__(256) void k_hh(const float* __restrict__ RH,
                                            const float* __restrict__ REC,
                                            const float* __restrict__ M,
                                            float* __restrict__ S) {
    const int row0 = blockIdx.y * 64;
    const int col0 = blockIdx.x * 64;   // within [0,128)
    __shared__ float As[16][68];
    __shared__ float Bs[16][68];
    const int tid = threadIdx.x;
    const int tr = tid >> 4, tc = tid & 15;
    float acc[4][4] = {};
    for (int k0 = 0; k0 < U_; k0 += 16) {
        __syncthreads();
#pragma unroll
        for (int j = 0; j < 4; ++j) {
            int f = tid + 256 * j;
            int m = f >> 4, k = f & 15;
            As[k][m] = RH[(size_t)(row0 + m) * U_ + k0 + k];
            int kb = f >> 6, n = f & 63;
            Bs[kb][n] = REC[(size_t)(k0 + kb) * TH_ + 256 + col0 + n];
        }
        __syncthreads();
#pragma unroll
        for (int k = 0; k < 16; ++k) {
            float4 av = *reinterpret_cast<const float4*>(&As[k][tr * 4]);
            float4 bv = *reinterpret_cast<const float4*>(&Bs[k][tc * 4]);
            float a[4] = {av.x, av.y, av.z, av.w};
            float b2[4] = {bv.x, bv.y, bv.z, bv.w};
#pragma unroll
            for (int i = 0; i < 4; ++i)
#pragma unroll
                for (int j = 0; j < 4; ++j) acc[i][j] = fmaf(a[i], b2[j], acc[i][j]);
        }
    }
#pragma unroll
    for (int i = 0; i < 4; ++i) {
        int R = row0 + tr * 4 + i;
#pragma unroll
        for (int j = 0; j < 4; ++j) {
            int u = col0 + tc * 4 + j;
            float z = M[(size_t)R * TH_ + u];
            float xh = M[(size_t)R * TH_ + 256 + u];
            float h = S[(size_t)R * U_ + u];
            float hh = tanhf(xh + acc[i][j]);
            S[(size_t)R * U_ + u] = z * h + (1.0f - z) * hh;
        }
    }
}

// ---------------------------------------------------------------------------
extern "C" void kernel_launch(void* const* d_in, const int* in_sizes, int n_in,
                              void* d_out, int out_size, void* d_ws, size_t ws_size,
                              hipStream_t stream) {
    const float* init_state = (const float*)d_in[0];
    const float* adj        = (const float*)d_in[1];
    const float* alpha      = (const float*)d_in[2];
    const float* w          = (const float*)d_in[3];
    const float* bb         = (const float*)d_in[4];
    const float* gk         = (const float*)d_in[5];
    const float* grk        = (const float*)d_in[6];
    const float* gbias      = (const float*)d_in[7];
    float* state = (float*)d_out;               // [BN x U], evolves in place
    float* ws = (float*)d_ws;

    // workspace layout (floats), with aliasing:
    //  H  : [0, 8388608)        (B*E*N*U)     — dead after k_neigh each step
    //  M  : [0, 3145728)        (BN*3U)       — aliases H (written after H dies)
    //  RH : [3145728, 4194304)  (BN*U)        — aliases H tail
    //  NG : [8388608, 16777216) (B*N*E*U)
    float* H  = ws;
    float* M  = ws;
    float* RH = ws + 3145728;
    float* NG = ws + 8388608;

    hipMemcpyAsync(state, init_state, (size_t)BN_ * U_ * sizeof(float),
                   hipMemcpyDeviceToDevice, stream);

    for (int step = 0; step < NSTEP; ++step) {
        k_edge<<<dim3(U_ / 64, BN_ / 64, E_), 256, 0, stream>>>(state, w, bb, H);
        k_neigh<<<dim3(U_ / 64, N_ / 64, B_ * E_), 256, 0, stream>>>(adj, H, alpha, NG);
        k_gruin<<<dim3(TH_ / 64, BN_ / 64), 256, 0, stream>>>(NG, gk, gbias, M);
        k_reczr<<<dim3(256 / 64, BN_ / 64), 256, 0, stream>>>(state, grk, M);
        k_gates<<<dim3((BN_ * U_) / 256), 256, 0, stream>>>(state, M, RH);
        k_hh<<<dim3(U_ / 64, BN_ / 64), 256, 0, stream>>>(RH, grk, M, state);
    }
}

// Round 7
// 653.991 us; speedup vs baseline: 1.6820x; 1.6820x over previous
//
#include <hip/hip_runtime.h>

// GGNN B=16, N=512, U=128, E=8, 3 steps — split-bf16 MFMA version.
// Each fp32 operand x is represented as hi=bf16(x), lo=bf16(x-hi);
// products use 3 MFMAs: Ah*Bh + Al*Bh + Ah*Bl (fp32 accumulate).
// GEMM skeleton: 128x128 tile, 4 waves (2x2), each wave 64x64 via 4x4
// frags of mfma_f32_16x16x32_bf16. LDS rows padded to 40 shorts (80 B).

typedef __attribute__((ext_vector_type(8))) short short8;
typedef __attribute__((ext_vector_type(4))) short short4v;
typedef __attribute__((ext_vector_type(4))) float f32x4;

__device__ __forceinline__ short bfs(float f) {
    __bf16 h = (__bf16)f;
    return __builtin_bit_cast(short, h);
}
__device__ __forceinline__ void split2(float x, short& hi, short& lo) {
    __bf16 h = (__bf16)x;
    hi = __builtin_bit_cast(short, h);
    __bf16 l = (__bf16)(x - (float)h);
    lo = __builtin_bit_cast(short, l);
}
__device__ __forceinline__ float sigm(float x) { return 1.0f / (1.0f + __expf(-x)); }

#define LDP 40   // padded LDS row stride (shorts) for BK=32 tiles

#define MFMA3(acc, ah, al, bh, bl)                                             \
    acc = __builtin_amdgcn_mfma_f32_16x16x32_bf16(ah, bh, acc, 0, 0, 0);       \
    acc = __builtin_amdgcn_mfma_f32_16x16x32_bf16(al, bh, acc, 0, 0, 0);       \
    acc = __builtin_amdgcn_mfma_f32_16x16x32_bf16(ah, bl, acc, 0, 0, 0);

// ---------------------------------------------------------------------------
// prologue: hi/lo weight transposes + initial state + sigmoid(alpha)
__global__ __launch_bounds__(256) void k_prep(const float* __restrict__ w,
                                              const float* __restrict__ gk,
                                              const float* __restrict__ grk,
                                              const float* __restrict__ alpha,
                                              const float* __restrict__ init_state,
                                              short* __restrict__ Wt_hi, short* __restrict__ Wt_lo,
                                              short* __restrict__ GKt_hi, short* __restrict__ GKt_lo,
                                              short* __restrict__ REC_hi, short* __restrict__ REC_lo,
                                              short* __restrict__ NG2_hi, short* __restrict__ NG2_lo,
                                              float* __restrict__ siga) {
    int idx = blockIdx.x * 256 + threadIdx.x;
    if (idx < 131072) {
        int e = idx >> 14, rem = idx & 16383, u = rem >> 7, d = rem & 127;
        split2(w[e * 16384 + d * 128 + u], Wt_hi[idx], Wt_lo[idx]);
    } else if (idx < 573440) {
        int i2 = idx - 131072;
        int c = i2 / 1152, k = i2 - c * 1152;
        float v = (k < 1024) ? gk[k * 384 + c]
                             : ((c < 256) ? grk[(k - 1024) * 384 + c] : 0.0f);
        split2(v, GKt_hi[i2], GKt_lo[i2]);
    } else if (idx < 589824) {
        int i2 = idx - 573440;
        int u = i2 >> 7, d = i2 & 127;
        split2(grk[d * 384 + 256 + u], REC_hi[i2], REC_lo[i2]);
    } else if (idx < 1638400) {
        int i2 = idx - 589824;
        int r = i2 >> 7, d = i2 & 127;
        split2(init_state[i2], NG2_hi[(size_t)r * 1152 + 1024 + d],
                              NG2_lo[(size_t)r * 1152 + 1024 + d]);
    } else if (idx < 1638408) {
        int e = idx - 1638400;
        siga[e] = sigm(alpha[e]);
    }
}

// ---------------------------------------------------------------------------
// K1: Ht[b][e][u][n] = siga[e]*( sum_d Wt[e][u][d]*S[bn][d] + bias[e][u] )
// grid (64 over bn, 8 e), block 256
__global__ __launch_bounds__(256) void k_edge(const short* __restrict__ Wt_hi,
                                              const short* __restrict__ Wt_lo,
                                              const short* __restrict__ NG2_hi,
                                              const short* __restrict__ NG2_lo,
                                              const float* __restrict__ bias,
                                              const float* __restrict__ siga,
                                              short* __restrict__ Ht_hi,
                                              short* __restrict__ Ht_lo) {
    const int e = blockIdx.y;
    const int col0 = blockIdx.x * 128;             // over bn
    __shared__ short Ash[128 * LDP], Asl[128 * LDP];
    __shared__ short Bsh[128 * LDP], Bsl[128 * LDP];
    const int tid = threadIdx.x;
    const int lane = tid & 63, wave = tid >> 6;
    const int wr = wave >> 1, wc = wave & 1;
    const int l15 = lane & 15, g8 = (lane >> 4) * 8;
    const short* wh = Wt_hi + e * 16384;
    const short* wl = Wt_lo + e * 16384;
    f32x4 acc[4][4] = {};
    for (int k0 = 0; k0 < 128; k0 += 32) {
        __syncthreads();
#pragma unroll
        for (int it = 0; it < 2; ++it) {          // A: 128 rows(u) x 32(d)
            int idx = tid + it * 256;
            int r = idx >> 2, gg = idx & 3;
            *(short8*)&Ash[r * LDP + gg * 8] = *(const short8*)&wh[r * 128 + k0 + gg * 8];
            *(short8*)&Asl[r * LDP + gg * 8] = *(const short8*)&wl[r * 128 + k0 + gg * 8];
        }
#pragma unroll
        for (int it = 0; it < 2; ++it) {          // B: 128 rows(bn) x 32(d)
            int idx = tid + it * 256;
            int r = idx >> 2, gg = idx & 3;
            size_t src = (size_t)(col0 + r) * 1152 + 1024 + k0 + gg * 8;
            *(short8*)&Bsh[r * LDP + gg * 8] = *(const short8*)&NG2_hi[src];
            *(short8*)&Bsl[r * LDP + gg * 8] = *(const short8*)&NG2_lo[src];
        }
        __syncthreads();
        short8 ah[4], al[4], bh[4], bl[4];
#pragma unroll
        for (int f = 0; f < 4; ++f) {
            int ra = (wr * 64 + f * 16 + l15) * LDP + g8;
            int rb = (wc * 64 + f * 16 + l15) * LDP + g8;
            ah[f] = *(const short8*)&Ash[ra]; al[f] = *(const short8*)&Asl[ra];
            bh[f] = *(const short8*)&Bsh[rb]; bl[f] = *(const short8*)&Bsl[rb];
        }
#pragma unroll
        for (int i = 0; i < 4; ++i)
#pragma unroll
            for (int j = 0; j < 4; ++j) { MFMA3(acc[i][j], ah[i], al[i], bh[j], bl[j]); }
    }
    const float sa = siga[e];
#pragma unroll
    for (int i = 0; i < 4; ++i) {
#pragma unroll
        for (int j = 0; j < 4; ++j) {
#pragma unroll
            for (int rg = 0; rg < 4; ++rg) {
                int u = wr * 64 + i * 16 + (lane >> 4) * 4 + rg;
                int bn = col0 + wc * 64 + j * 16 + l15;
                int b_ = bn >> 9, n = bn & 511;
                float v = sa * (acc[i][j][rg] + bias[e * 128 + u]);
                size_t o = ((size_t)(b_ * 8 + e) * 128 + u) * 512 + n;
                split2(v, Ht_hi[o], Ht_lo[o]);
            }
        }
    }
}

// ---------------------------------------------------------------------------
// K2: NG2[b*512+n][e*128+u] = sum_m adj[b][e][n][m] * Ht[b][e][u][m]
// grid (4 over n, 128 be), block 256
__global__ __launch_bounds__(256) void k_neigh(const float* __restrict__ adj,
                                               const short* __restrict__ Ht_hi,
                                               const short* __restrict__ Ht_lo,
                                               short* __restrict__ NG2_hi,
                                               short* __restrict__ NG2_lo) {
    const int be = blockIdx.y;
    const int b = be >> 3, e = be & 7;
    const int row0 = blockIdx.x * 128;             // over n
    __shared__ short Ash[128 * LDP], Asl[128 * LDP];
    __shared__ short Bsh[128 * LDP], Bsl[128 * LDP];
    const int tid = threadIdx.x;
    const int lane = tid & 63, wave = tid >> 6;
    const int wr = wave >> 1, wc = wave & 1;
    const int l15 = lane & 15, g8 = (lane >> 4) * 8;
    const float* A = adj + (size_t)be * 262144;
    const short* Bh = Ht_hi + (size_t)be * 65536;
    const short* Bl = Ht_lo + (size_t)be * 65536;
    f32x4 acc[4][4] = {};
    for (int k0 = 0; k0 < 512; k0 += 32) {
        __syncthreads();
#pragma unroll
        for (int it = 0; it < 4; ++it) {          // A: 128(n) x 32(m) fp32->hi/lo
            int idx = tid + it * 256;
            int r = idx >> 3, c4 = idx & 7;
            float4 v = *(const float4*)&A[(size_t)(row0 + r) * 512 + k0 + c4 * 4];
            short4v sh, sl;
            short h0, l0;
            split2(v.x, h0, l0); sh.x = h0; sl.x = l0;
            split2(v.y, h0, l0); sh.y = h0; sl.y = l0;
            split2(v.z, h0, l0); sh.z = h0; sl.z = l0;
            split2(v.w, h0, l0); sh.w = h0; sl.w = l0;
            *(short4v*)&Ash[r * LDP + c4 * 4] = sh;
            *(short4v*)&Asl[r * LDP + c4 * 4] = sl;
        }
#pragma unroll
        for (int it = 0; it < 2; ++it) {          // B: 128(u) x 32(m)
            int idx = tid + it * 256;
            int r = idx >> 2, gg = idx & 3;
            *(short8*)&Bsh[r * LDP + gg * 8] = *(const short8*)&Bh[r * 512 + k0 + gg * 8];
            *(short8*)&Bsl[r * LDP + gg * 8] = *(const short8*)&Bl[r * 512 + k0 + gg * 8];
        }
        __syncthreads();
        short8 ah[4], al[4], bh[4], bl[4];
#pragma unroll
        for (int f = 0; f < 4; ++f) {
            int ra = (wr * 64 + f * 16 + l15) * LDP + g8;
            int rb = (wc * 64 + f * 16 + l15) * LDP + g8;
            ah[f] = *(const short8*)&Ash[ra]; al[f] = *(const short8*)&Asl[ra];
            bh[f] = *(const short8*)&Bsh[rb]; bl[f] = *(const short8*)&Bsl[rb];
        }
#pragma unroll
        for (int i = 0; i < 4; ++i)
#pragma unroll
            for (int j = 0; j < 4; ++j) { MFMA3(acc[i][j], ah[i], al[i], bh[j], bl[j]); }
    }
#pragma unroll
    for (int i = 0; i < 4; ++i) {
#pragma unroll
        for (int j = 0; j < 4; ++j) {
#pragma unroll
            for (int rg = 0; rg < 4; ++rg) {
                int n = row0 + wr * 64 + i * 16 + (lane >> 4) * 4 + rg;
                int u = wc * 64 + j * 16 + l15;
                size_t o = (size_t)(b * 512 + n) * 1152 + e * 128 + u;
                split2(acc[i][j][rg], NG2_hi[o], NG2_lo[o]);
            }
        }
    }
}

// ---------------------------------------------------------------------------
// K3: M[8192 x 384] = NG2[8192 x 1152] @ GK2 + gbias   (fp32 out)
// grid (3 colblocks, 64 rowblocks), block 256
__global__ __launch_bounds__(256) void k_gruin(const short* __restrict__ NG2_hi,
                                               const short* __restrict__ NG2_lo,
                                               const short* __restrict__ GKt_hi,
                                               const short* __restrict__ GKt_lo,
                                               const float* __restrict__ gbias,
                                               float* __restrict__ M) {
    const int col0 = blockIdx.x * 128;
    const int row0 = blockIdx.y * 128;
    __shared__ short Ash[128 * LDP], Asl[128 * LDP];
    __shared__ short Bsh[128 * LDP], Bsl[128 * LDP];
    const int tid = threadIdx.x;
    const int lane = tid & 63, wave = tid >> 6;
    const int wr = wave >> 1, wc = wave & 1;
    const int l15 = lane & 15, g8 = (lane >> 4) * 8;
    f32x4 acc[4][4] = {};
    for (int k0 = 0; k0 < 1152; k0 += 32) {
        __syncthreads();
#pragma unroll
        for (int it = 0; it < 2; ++it) {
            int idx = tid + it * 256;
            int r = idx >> 2, gg = idx & 3;
            size_t src = (size_t)(row0 + r) * 1152 + k0 + gg * 8;
            *(short8*)&Ash[r * LDP + gg * 8] = *(const short8*)&NG2_hi[src];
            *(short8*)&Asl[r * LDP + gg * 8] = *(const short8*)&NG2_lo[src];
        }
#pragma unroll
        for (int it = 0; it < 2; ++it) {
            int idx = tid + it * 256;
            int r = idx >> 2, gg = idx & 3;
            size_t src = (size_t)(col0 + r) * 1152 + k0 + gg * 8;
            *(short8*)&Bsh[r * LDP + gg * 8] = *(const short8*)&GKt_hi[src];
            *(short8*)&Bsl[r * LDP + gg * 8] = *(const short8*)&GKt_lo[src];
        }
        __syncthreads();
        short8 ah[4], al[4], bh[4], bl[4];
#pragma unroll
        for (int f = 0; f < 4; ++f) {
            int ra = (wr * 64 + f * 16 + l15) * LDP + g8;
            int rb = (wc * 64 + f * 16 + l15) * LDP + g8;
            ah[f] = *(const short8*)&Ash[ra]; al[f] = *(const short8*)&Asl[ra];
            bh[f] = *(const short8*)&Bsh[rb]; bl[f] = *(const short8*)&Bsl[rb];
        }
#pragma unroll
        for (int i = 0; i < 4; ++i)
#pragma unroll
            for (int j = 0; j < 4; ++j) { MFMA3(acc[i][j], ah[i], al[i], bh[j], bl[j]); }
    }
#pragma unroll
    for (int i = 0; i < 4; ++i) {
#pragma unroll
        for (int j = 0; j < 4; ++j) {
#pragma unroll
            for (int rg = 0; rg < 4; ++rg) {
                int R = row0 + wr * 64 + i * 16 + (lane >> 4) * 4 + rg;
                int c = col0 + wc * 64 + j * 16 + l15;
                M[(size_t)R * 384 + c] = acc[i][j][rg] + gbias[c];
            }
        }
    }
}

// ---------------------------------------------------------------------------
// K4 (fused gates + hh GEMM + GRU update), BK=32 loop over K=128:
//   r = sigm(M[:,128:256]); A = split(r*state); hh_lin = A @ RECht^T
//   z = sigm(M[:,0:128]); s' = z*h + (1-z)*tanh(M[:,256:384]+hh_lin)
//   d_out = s' (fp32); NG2[:,1024:] = split(s')
// grid (64 rowblocks), block 256
__global__ __launch_bounds__(256) void k_hh(const float* __restrict__ M,
                                            const short* __restrict__ REC_hi,
                                            const short* __restrict__ REC_lo,
                                            float* __restrict__ S,
                                            short* __restrict__ NG2_hi,
                                            short* __restrict__ NG2_lo) {
    const int row0 = blockIdx.x * 128;
    __shared__ short Ash[128 * LDP], Asl[128 * LDP];
    __shared__ short Bsh[128 * LDP], Bsl[128 * LDP];
    const int tid = threadIdx.x;
    const int lane = tid & 63, wave = tid >> 6;
    const int wr = wave >> 1, wc = wave & 1;
    const int l15 = lane & 15, g8 = (lane >> 4) * 8;
    f32x4 acc[4][4] = {};
    for (int k0 = 0; k0 < 128; k0 += 32) {
        __syncthreads();
#pragma unroll
        for (int it = 0; it < 4; ++it) {          // A: r*h, fp32->hi/lo
            int idx = tid + it * 256;
            int r = idx >> 3, c4 = idx & 7;
            float4 m4 = *(const float4*)&M[(size_t)(row0 + r) * 384 + 128 + k0 + c4 * 4];
            float4 h4 = *(const float4*)&S[(size_t)(row0 + r) * 128 + k0 + c4 * 4];
            short4v sh, sl;
            short h0, l0;
            split2(sigm(m4.x) * h4.x, h0, l0); sh.x = h0; sl.x = l0;
            split2(sigm(m4.y) * h4.y, h0, l0); sh.y = h0; sl.y = l0;
            split2(sigm(m4.z) * h4.z, h0, l0); sh.z = h0; sl.z = l0;
            split2(sigm(m4.w) * h4.w, h0, l0); sh.w = h0; sl.w = l0;
            *(short4v*)&Ash[r * LDP + c4 * 4] = sh;
            *(short4v*)&Asl[r * LDP + c4 * 4] = sl;
        }
#pragma unroll
        for (int it = 0; it < 2; ++it) {          // B: RECht 128(u) x 32(d)
            int idx = tid + it * 256;
            int r = idx >> 2, gg = idx & 3;
            *(short8*)&Bsh[r * LDP + gg * 8] = *(const short8*)&REC_hi[r * 128 + k0 + gg * 8];
            *(short8*)&Bsl[r * LDP + gg * 8] = *(const short8*)&REC_lo[r * 128 + k0 + gg * 8];
        }
        __syncthreads();
        short8 ah[4], al[4], bh[4], bl[4];
#pragma unroll
        for (int f = 0; f < 4; ++f) {
            int ra = (wr * 64 + f * 16 + l15) * LDP + g8;
            int rb = (wc * 64 + f * 16 + l15) * LDP + g8;
            ah[f] = *(const short8*)&Ash[ra]; al[f] = *(const short8*)&Asl[ra];
            bh[f] = *(const short8*)&Bsh[rb]; bl[f] = *(const short8*)&Bsl[rb];
        }
#pragma unroll
        for (int i = 0; i < 4; ++i)
#pragma unroll
            for (int j = 0; j < 4; ++j) { MFMA3(acc[i][j], ah[i], al[i], bh[j], bl[j]); }
    }
#pragma unroll
    for (int i = 0; i < 4; ++i) {
#pragma unroll
        for (int j = 0; j < 4; ++j) {
#pragma unroll
            for (int rg = 0; rg < 4; ++rg) {
                int R = row0 + wr * 64 + i * 16 + (lane >> 4) * 4 + rg;
                int u = wc * 64 + j * 16 + l15;
                float z = sigm(M[(size_t)R * 384 + u]);
                float xh = M[(size_t)R * 384 + 256 + u];
                float h = S[(size_t)R * 128 + u];
                float hh = tanhf(xh + acc[i][j][rg]);
                float sn = z * h + (1.0f - z) * hh;
                S[(size_t)R * 128 + u] = sn;
                split2(sn, NG2_hi[(size_t)R * 1152 + 1024 + u],
                           NG2_lo[(size_t)R * 1152 + 1024 + u]);
            }
        }
    }
}

// ---------------------------------------------------------------------------
extern "C" void kernel_launch(void* const* d_in, const int* in_sizes, int n_in,
                              void* d_out, int out_size, void* d_ws, size_t ws_size,
                              hipStream_t stream) {
    const float* init_state = (const float*)d_in[0];
    const float* adj        = (const float*)d_in[1];
    const float* alpha      = (const float*)d_in[2];
    const float* w          = (const float*)d_in[3];
    const float* bias       = (const float*)d_in[4];
    const float* gk         = (const float*)d_in[5];
    const float* grk        = (const float*)d_in[6];
    const float* gbias      = (const float*)d_in[7];
    float* state = (float*)d_out;

    // ws layout (bytes), total ~70.3 MiB:
    //  NG2_hi bf16 [8192][1152] @ 0          (18874368)  cols 1024.. = state hi
    //  NG2_lo                  @ 18874368    (18874368)
    //  Ht_hi  bf16 [128][128][512] @ 37748736 (16777216)  M fp32 aliases (dead Ht)
    //  Ht_lo                   @ 54525952    (16777216)
    //  Wt_hi/lo                @ 71303168    (2x262144)
    //  GKt_hi/lo               @ 71827456    (2x884736)
    //  REC_hi/lo               @ 73596928    (2x32768)
    //  siga                    @ 73662464    (32)
    char* ws = (char*)d_ws;
    short* NG2_hi = (short*)(ws);
    short* NG2_lo = (short*)(ws + 18874368);
    short* Ht_hi  = (short*)(ws + 37748736);
    float* M      = (float*)(ws + 37748736);   // aliases Ht_hi (disjoint lifetime)
    short* Ht_lo  = (short*)(ws + 54525952);
    short* Wt_hi  = (short*)(ws + 71303168);
    short* Wt_lo  = (short*)(ws + 71565312);
    short* GKt_hi = (short*)(ws + 71827456);
    short* GKt_lo = (short*)(ws + 72712192);
    short* REC_hi = (short*)(ws + 73596928);
    short* REC_lo = (short*)(ws + 73629696);
    float* siga   = (float*)(ws + 73662464);

    k_prep<<<dim3(6401), 256, 0, stream>>>(w, gk, grk, alpha, init_state,
                                           Wt_hi, Wt_lo, GKt_hi, GKt_lo,
                                           REC_hi, REC_lo, NG2_hi, NG2_lo, siga);
    (void)hipMemcpyAsync(state, init_state, (size_t)8192 * 128 * sizeof(float),
                         hipMemcpyDeviceToDevice, stream);

    for (int step = 0; step < 3; ++step) {
        k_edge <<<dim3(64, 8),  256, 0, stream>>>(Wt_hi, Wt_lo, NG2_hi, NG2_lo,
                                                  bias, siga, Ht_hi, Ht_lo);
        k_neigh<<<dim3(4, 128), 256, 0, stream>>>(adj, Ht_hi, Ht_lo, NG2_hi, NG2_lo);
        k_gruin<<<dim3(3, 64),  256, 0, stream>>>(NG2_hi, NG2_lo, GKt_hi, GKt_lo,
                                                  gbias, M);
        k_hh   <<<dim3(64),     256, 0, stream>>>(M, REC_hi, REC_lo, state,
                                                  NG2_hi, NG2_lo);
    }
}

// Round 8
// 587.304 us; speedup vs baseline: 1.8730x; 1.1135x over previous
//
#include <hip/hip_runtime.h>

// GGNN B=16, N=512, U=128, E=8, 3 steps — split-bf16 MFMA version.
// Each fp32 operand x is represented as hi=bf16(x), lo=bf16(x-hi);
// products use 3 MFMAs: Ah*Bh + Al*Bh + Ah*Bl (fp32 accumulate).
// GEMM skeleton: 128x128 tile, 4 waves (2x2), each wave 64x64 via 4x4
// frags of mfma_f32_16x16x32_bf16. LDS rows padded to 40 shorts (80 B).
// R8: k_hh re-tiled to 32-row blocks (256 blocks, all CUs), LDS round-trip
// for hh_lin, fully-coalesced float4 GRU-update phase (was latency-bound:
// 90us/dispatch @ 2.7% occupancy, 64 blocks, scattered scalar epilogue).

typedef __attribute__((ext_vector_type(8))) short short8;
typedef __attribute__((ext_vector_type(4))) short short4v;
typedef __attribute__((ext_vector_type(4))) float f32x4;

__device__ __forceinline__ short bfs(float f) {
    __bf16 h = (__bf16)f;
    return __builtin_bit_cast(short, h);
}
__device__ __forceinline__ void split2(float x, short& hi, short& lo) {
    __bf16 h = (__bf16)x;
    hi = __builtin_bit_cast(short, h);
    __bf16 l = (__bf16)(x - (float)h);
    lo = __builtin_bit_cast(short, l);
}
__device__ __forceinline__ float sigm(float x) { return 1.0f / (1.0f + __expf(-x)); }

#define LDP 40   // padded LDS row stride (shorts) for BK=32 tiles
#define LDH 136  // padded LDS row stride (shorts) for K=128 single-shot tiles

#define MFMA3(acc, ah, al, bh, bl)                                             \
    acc = __builtin_amdgcn_mfma_f32_16x16x32_bf16(ah, bh, acc, 0, 0, 0);       \
    acc = __builtin_amdgcn_mfma_f32_16x16x32_bf16(al, bh, acc, 0, 0, 0);       \
    acc = __builtin_amdgcn_mfma_f32_16x16x32_bf16(ah, bl, acc, 0, 0, 0);

// ---------------------------------------------------------------------------
// prologue: hi/lo weight transposes + initial state + sigmoid(alpha)
__global__ __launch_bounds__(256) void k_prep(const float* __restrict__ w,
                                              const float* __restrict__ gk,
                                              const float* __restrict__ grk,
                                              const float* __restrict__ alpha,
                                              const float* __restrict__ init_state,
                                              short* __restrict__ Wt_hi, short* __restrict__ Wt_lo,
                                              short* __restrict__ GKt_hi, short* __restrict__ GKt_lo,
                                              short* __restrict__ REC_hi, short* __restrict__ REC_lo,
                                              short* __restrict__ NG2_hi, short* __restrict__ NG2_lo,
                                              float* __restrict__ siga) {
    int idx = blockIdx.x * 256 + threadIdx.x;
    if (idx < 131072) {
        int e = idx >> 14, rem = idx & 16383, u = rem >> 7, d = rem & 127;
        split2(w[e * 16384 + d * 128 + u], Wt_hi[idx], Wt_lo[idx]);
    } else if (idx < 573440) {
        int i2 = idx - 131072;
        int c = i2 / 1152, k = i2 - c * 1152;
        float v = (k < 1024) ? gk[k * 384 + c]
                             : ((c < 256) ? grk[(k - 1024) * 384 + c] : 0.0f);
        split2(v, GKt_hi[i2], GKt_lo[i2]);
    } else if (idx < 589824) {
        int i2 = idx - 573440;
        int u = i2 >> 7, d = i2 & 127;
        split2(grk[d * 384 + 256 + u], REC_hi[i2], REC_lo[i2]);
    } else if (idx < 1638400) {
        int i2 = idx - 589824;
        int r = i2 >> 7, d = i2 & 127;
        split2(init_state[i2], NG2_hi[(size_t)r * 1152 + 1024 + d],
                              NG2_lo[(size_t)r * 1152 + 1024 + d]);
    } else if (idx < 1638408) {
        int e = idx - 1638400;
        siga[e] = sigm(alpha[e]);
    }
}

// ---------------------------------------------------------------------------
// K1: Ht[b][e][u][n] = siga[e]*( sum_d Wt[e][u][d]*S[bn][d] + bias[e][u] )
// grid (64 over bn, 8 e), block 256
__global__ __launch_bounds__(256) void k_edge(const short* __restrict__ Wt_hi,
                                              const short* __restrict__ Wt_lo,
                                              const short* __restrict__ NG2_hi,
                                              const short* __restrict__ NG2_lo,
                                              const float* __restrict__ bias,
                                              const float* __restrict__ siga,
                                              short* __restrict__ Ht_hi,
                                              short* __restrict__ Ht_lo) {
    const int e = blockIdx.y;
    const int col0 = blockIdx.x * 128;             // over bn
    __shared__ short Ash[128 * LDP], Asl[128 * LDP];
    __shared__ short Bsh[128 * LDP], Bsl[128 * LDP];
    const int tid = threadIdx.x;
    const int lane = tid & 63, wave = tid >> 6;
    const int wr = wave >> 1, wc = wave & 1;
    const int l15 = lane & 15, g8 = (lane >> 4) * 8;
    const short* wh = Wt_hi + e * 16384;
    const short* wl = Wt_lo + e * 16384;
    f32x4 acc[4][4] = {};
    for (int k0 = 0; k0 < 128; k0 += 32) {
        __syncthreads();
#pragma unroll
        for (int it = 0; it < 2; ++it) {          // A: 128 rows(u) x 32(d)
            int idx = tid + it * 256;
            int r = idx >> 2, gg = idx & 3;
            *(short8*)&Ash[r * LDP + gg * 8] = *(const short8*)&wh[r * 128 + k0 + gg * 8];
            *(short8*)&Asl[r * LDP + gg * 8] = *(const short8*)&wl[r * 128 + k0 + gg * 8];
        }
#pragma unroll
        for (int it = 0; it < 2; ++it) {          // B: 128 rows(bn) x 32(d)
            int idx = tid + it * 256;
            int r = idx >> 2, gg = idx & 3;
            size_t src = (size_t)(col0 + r) * 1152 + 1024 + k0 + gg * 8;
            *(short8*)&Bsh[r * LDP + gg * 8] = *(const short8*)&NG2_hi[src];
            *(short8*)&Bsl[r * LDP + gg * 8] = *(const short8*)&NG2_lo[src];
        }
        __syncthreads();
        short8 ah[4], al[4], bh[4], bl[4];
#pragma unroll
        for (int f = 0; f < 4; ++f) {
            int ra = (wr * 64 + f * 16 + l15) * LDP + g8;
            int rb = (wc * 64 + f * 16 + l15) * LDP + g8;
            ah[f] = *(const short8*)&Ash[ra]; al[f] = *(const short8*)&Asl[ra];
            bh[f] = *(const short8*)&Bsh[rb]; bl[f] = *(const short8*)&Bsl[rb];
        }
#pragma unroll
        for (int i = 0; i < 4; ++i)
#pragma unroll
            for (int j = 0; j < 4; ++j) { MFMA3(acc[i][j], ah[i], al[i], bh[j], bl[j]); }
    }
    const float sa = siga[e];
#pragma unroll
    for (int i = 0; i < 4; ++i) {
#pragma unroll
        for (int j = 0; j < 4; ++j) {
#pragma unroll
            for (int rg = 0; rg < 4; ++rg) {
                int u = wr * 64 + i * 16 + (lane >> 4) * 4 + rg;
                int bn = col0 + wc * 64 + j * 16 + l15;
                int b_ = bn >> 9, n = bn & 511;
                float v = sa * (acc[i][j][rg] + bias[e * 128 + u]);
                size_t o = ((size_t)(b_ * 8 + e) * 128 + u) * 512 + n;
                split2(v, Ht_hi[o], Ht_lo[o]);
            }
        }
    }
}

// ---------------------------------------------------------------------------
// K2: NG2[b*512+n][e*128+u] = sum_m adj[b][e][n][m] * Ht[b][e][u][m]
// grid (4 over n, 128 be), block 256
__global__ __launch_bounds__(256) void k_neigh(const float* __restrict__ adj,
                                               const short* __restrict__ Ht_hi,
                                               const short* __restrict__ Ht_lo,
                                               short* __restrict__ NG2_hi,
                                               short* __restrict__ NG2_lo) {
    const int be = blockIdx.y;
    const int b = be >> 3, e = be & 7;
    const int row0 = blockIdx.x * 128;             // over n
    __shared__ short Ash[128 * LDP], Asl[128 * LDP];
    __shared__ short Bsh[128 * LDP], Bsl[128 * LDP];
    const int tid = threadIdx.x;
    const int lane = tid & 63, wave = tid >> 6;
    const int wr = wave >> 1, wc = wave & 1;
    const int l15 = lane & 15, g8 = (lane >> 4) * 8;
    const float* A = adj + (size_t)be * 262144;
    const short* Bh = Ht_hi + (size_t)be * 65536;
    const short* Bl = Ht_lo + (size_t)be * 65536;
    f32x4 acc[4][4] = {};
    for (int k0 = 0; k0 < 512; k0 += 32) {
        __syncthreads();
#pragma unroll
        for (int it = 0; it < 4; ++it) {          // A: 128(n) x 32(m) fp32->hi/lo
            int idx = tid + it * 256;
            int r = idx >> 3, c4 = idx & 7;
            float4 v = *(const float4*)&A[(size_t)(row0 + r) * 512 + k0 + c4 * 4];
            short4v sh, sl;
            short h0, l0;
            split2(v.x, h0, l0); sh.x = h0; sl.x = l0;
            split2(v.y, h0, l0); sh.y = h0; sl.y = l0;
            split2(v.z, h0, l0); sh.z = h0; sl.z = l0;
            split2(v.w, h0, l0); sh.w = h0; sl.w = l0;
            *(short4v*)&Ash[r * LDP + c4 * 4] = sh;
            *(short4v*)&Asl[r * LDP + c4 * 4] = sl;
        }
#pragma unroll
        for (int it = 0; it < 2; ++it) {          // B: 128(u) x 32(m)
            int idx = tid + it * 256;
            int r = idx >> 2, gg = idx & 3;
            *(short8*)&Bsh[r * LDP + gg * 8] = *(const short8*)&Bh[r * 512 + k0 + gg * 8];
            *(short8*)&Bsl[r * LDP + gg * 8] = *(const short8*)&Bl[r * 512 + k0 + gg * 8];
        }
        __syncthreads();
        short8 ah[4], al[4], bh[4], bl[4];
#pragma unroll
        for (int f = 0; f < 4; ++f) {
            int ra = (wr * 64 + f * 16 + l15) * LDP + g8;
            int rb = (wc * 64 + f * 16 + l15) * LDP + g8;
            ah[f] = *(const short8*)&Ash[ra]; al[f] = *(const short8*)&Asl[ra];
            bh[f] = *(const short8*)&Bsh[rb]; bl[f] = *(const short8*)&Bsl[rb];
        }
#pragma unroll
        for (int i = 0; i < 4; ++i)
#pragma unroll
            for (int j = 0; j < 4; ++j) { MFMA3(acc[i][j], ah[i], al[i], bh[j], bl[j]); }
    }
#pragma unroll
    for (int i = 0; i < 4; ++i) {
#pragma unroll
        for (int j = 0; j < 4; ++j) {
#pragma unroll
            for (int rg = 0; rg < 4; ++rg) {
                int n = row0 + wr * 64 + i * 16 + (lane >> 4) * 4 + rg;
                int u = wc * 64 + j * 16 + l15;
                size_t o = (size_t)(b * 512 + n) * 1152 + e * 128 + u;
                split2(acc[i][j][rg], NG2_hi[o], NG2_lo[o]);
            }
        }
    }
}

// ---------------------------------------------------------------------------
// K3: M[8192 x 384] = NG2[8192 x 1152] @ GK2 + gbias   (fp32 out)
// grid (3 colblocks, 64 rowblocks), block 256
__global__ __launch_bounds__(256) void k_gruin(const short* __restrict__ NG2_hi,
                                               const short* __restrict__ NG2_lo,
                                               const short* __restrict__ GKt_hi,
                                               const short* __restrict__ GKt_lo,
                                               const float* __restrict__ gbias,
                                               float* __restrict__ M) {
    const int col0 = blockIdx.x * 128;
    const int row0 = blockIdx.y * 128;
    __shared__ short Ash[128 * LDP], Asl[128 * LDP];
    __shared__ short Bsh[128 * LDP], Bsl[128 * LDP];
    const int tid = threadIdx.x;
    const int lane = tid & 63, wave = tid >> 6;
    const int wr = wave >> 1, wc = wave & 1;
    const int l15 = lane & 15, g8 = (lane >> 4) * 8;
    f32x4 acc[4][4] = {};
    for (int k0 = 0; k0 < 1152; k0 += 32) {
        __syncthreads();
#pragma unroll
        for (int it = 0; it < 2; ++it) {
            int idx = tid + it * 256;
            int r = idx >> 2, gg = idx & 3;
            size_t src = (size_t)(row0 + r) * 1152 + k0 + gg * 8;
            *(short8*)&Ash[r * LDP + gg * 8] = *(const short8*)&NG2_hi[src];
            *(short8*)&Asl[r * LDP + gg * 8] = *(const short8*)&NG2_lo[src];
        }
#pragma unroll
        for (int it = 0; it < 2; ++it) {
            int idx = tid + it * 256;
            int r = idx >> 2, gg = idx & 3;
            size_t src = (size_t)(col0 + r) * 1152 + k0 + gg * 8;
            *(short8*)&Bsh[r * LDP + gg * 8] = *(const short8*)&GKt_hi[src];
            *(short8*)&Bsl[r * LDP + gg * 8] = *(const short8*)&GKt_lo[src];
        }
        __syncthreads();
        short8 ah[4], al[4], bh[4], bl[4];
#pragma unroll
        for (int f = 0; f < 4; ++f) {
            int ra = (wr * 64 + f * 16 + l15) * LDP + g8;
            int rb = (wc * 64 + f * 16 + l15) * LDP + g8;
            ah[f] = *(const short8*)&Ash[ra]; al[f] = *(const short8*)&Asl[ra];
            bh[f] = *(const short8*)&Bsh[rb]; bl[f] = *(const short8*)&Bsl[rb];
        }
#pragma unroll
        for (int i = 0; i < 4; ++i)
#pragma unroll
            for (int j = 0; j < 4; ++j) { MFMA3(acc[i][j], ah[i], al[i], bh[j], bl[j]); }
    }
#pragma unroll
    for (int i = 0; i < 4; ++i) {
#pragma unroll
        for (int j = 0; j < 4; ++j) {
#pragma unroll
            for (int rg = 0; rg < 4; ++rg) {
                int R = row0 + wr * 64 + i * 16 + (lane >> 4) * 4 + rg;
                int c = col0 + wc * 64 + j * 16 + l15;
                M[(size_t)R * 384 + c] = acc[i][j][rg] + gbias[c];
            }
        }
    }
}

// ---------------------------------------------------------------------------
// K4 (fused gates + hh GEMM + GRU update), re-tiled for occupancy:
// 256 blocks x 32 rows. Phase 1: A = split(r*h) staged coalesced; B = RECht
// staged whole (K=128 single shot, no inner barriers). Phase 2: hh_lin ->
// LDS. Phase 3: coalesced float4 GRU update; writes S (d_out) + NG2 state.
// grid (256), block 256 (4 waves; wave w owns output cols w*32..w*32+31)
__global__ __launch_bounds__(256) void k_hh(const float* __restrict__ M,
                                            const short* __restrict__ REC_hi,
                                            const short* __restrict__ REC_lo,
                                            float* __restrict__ S,
                                            short* __restrict__ NG2_hi,
                                            short* __restrict__ NG2_lo) {
    const int row0 = blockIdx.x * 32;
    __shared__ short Ash[32 * LDH], Asl[32 * LDH];
    __shared__ short Bsh[128 * LDH], Bsl[128 * LDH];
    __shared__ float hh[32][132];
    const int tid = threadIdx.x;
    const int lane = tid & 63, wave = tid >> 6;
    const int l15 = lane & 15, g8 = (lane >> 4) * 8;

    // stage A = split(r*h): 32x128, 16 elems/thread, float4-coalesced
#pragma unroll
    for (int g = 0; g < 4; ++g) {
        int i2 = g * 1024 + tid * 4;
        int r = i2 >> 7, c = i2 & 127;
        float4 m4 = *(const float4*)&M[(size_t)(row0 + r) * 384 + 128 + c];
        float4 h4 = *(const float4*)&S[(size_t)(row0 + r) * 128 + c];
        short4v sh, sl;
        short h0, l0;
        split2(sigm(m4.x) * h4.x, h0, l0); sh.x = h0; sl.x = l0;
        split2(sigm(m4.y) * h4.y, h0, l0); sh.y = h0; sl.y = l0;
        split2(sigm(m4.z) * h4.z, h0, l0); sh.z = h0; sl.z = l0;
        split2(sigm(m4.w) * h4.w, h0, l0); sh.w = h0; sl.w = l0;
        *(short4v*)&Ash[r * LDH + c] = sh;
        *(short4v*)&Asl[r * LDH + c] = sl;
    }
    // stage B = RECht whole: 128x128
#pragma unroll
    for (int it = 0; it < 8; ++it) {
        int idx = tid + it * 256;
        int r = idx >> 4, gg = idx & 15;
        *(short8*)&Bsh[r * LDH + gg * 8] = *(const short8*)&REC_hi[r * 128 + gg * 8];
        *(short8*)&Bsl[r * LDH + gg * 8] = *(const short8*)&REC_lo[r * 128 + gg * 8];
    }
    __syncthreads();

    f32x4 acc[2][2] = {};
#pragma unroll
    for (int ks = 0; ks < 4; ++ks) {
        short8 ah[2], al_[2], bh[2], bl_[2];
#pragma unroll
        for (int f = 0; f < 2; ++f) {
            int ra = (f * 16 + l15) * LDH + ks * 32 + g8;
            int rb = (wave * 32 + f * 16 + l15) * LDH + ks * 32 + g8;
            ah[f] = *(const short8*)&Ash[ra]; al_[f] = *(const short8*)&Asl[ra];
            bh[f] = *(const short8*)&Bsh[rb]; bl_[f] = *(const short8*)&Bsl[rb];
        }
#pragma unroll
        for (int i = 0; i < 2; ++i)
#pragma unroll
            for (int j = 0; j < 2; ++j) { MFMA3(acc[i][j], ah[i], al_[i], bh[j], bl_[j]); }
    }
    // hh_lin -> LDS
#pragma unroll
    for (int i = 0; i < 2; ++i)
#pragma unroll
        for (int j = 0; j < 2; ++j)
#pragma unroll
            for (int rg = 0; rg < 4; ++rg) {
                int r = i * 16 + (lane >> 4) * 4 + rg;
                int c = wave * 32 + j * 16 + l15;
                hh[r][c] = acc[i][j][rg];
            }
    __syncthreads();

    // coalesced GRU update: 16 elems/thread (4x float4)
#pragma unroll
    for (int g = 0; g < 4; ++g) {
        int i2 = g * 1024 + tid * 4;
        int r = i2 >> 7, c = i2 & 127;
        int R = row0 + r;
        float4 z4 = *(const float4*)&M[(size_t)R * 384 + c];
        float4 x4 = *(const float4*)&M[(size_t)R * 384 + 256 + c];
        float4 h4 = *(const float4*)&S[(size_t)R * 128 + c];
        float4 l4 = *(const float4*)&hh[r][c];
        float4 sn;
        {
            float z = sigm(z4.x); sn.x = z * h4.x + (1.0f - z) * tanhf(x4.x + l4.x);
        }
        {
            float z = sigm(z4.y); sn.y = z * h4.y + (1.0f - z) * tanhf(x4.y + l4.y);
        }
        {
            float z = sigm(z4.z); sn.z = z * h4.z + (1.0f - z) * tanhf(x4.z + l4.z);
        }
        {
            float z = sigm(z4.w); sn.w = z * h4.w + (1.0f - z) * tanhf(x4.w + l4.w);
        }
        *(float4*)&S[(size_t)R * 128 + c] = sn;
        short4v sh, sl;
        short h0, l0;
        split2(sn.x, h0, l0); sh.x = h0; sl.x = l0;
        split2(sn.y, h0, l0); sh.y = h0; sl.y = l0;
        split2(sn.z, h0, l0); sh.z = h0; sl.z = l0;
        split2(sn.w, h0, l0); sh.w = h0; sl.w = l0;
        *(short4v*)&NG2_hi[(size_t)R * 1152 + 1024 + c] = sh;
        *(short4v*)&NG2_lo[(size_t)R * 1152 + 1024 + c] = sl;
    }
}

// ---------------------------------------------------------------------------
extern "C" void kernel_launch(void* const* d_in, const int* in_sizes, int n_in,
                              void* d_out, int out_size, void* d_ws, size_t ws_size,
                              hipStream_t stream) {
    const float* init_state = (const float*)d_in[0];
    const float* adj        = (const float*)d_in[1];
    const float* alpha      = (const float*)d_in[2];
    const float* w          = (const float*)d_in[3];
    const float* bias       = (const float*)d_in[4];
    const float* gk         = (const float*)d_in[5];
    const float* grk        = (const float*)d_in[6];
    const float* gbias      = (const float*)d_in[7];
    float* state = (float*)d_out;

    // ws layout (bytes), total ~70.3 MiB:
    //  NG2_hi bf16 [8192][1152] @ 0          (18874368)  cols 1024.. = state hi
    //  NG2_lo                  @ 18874368    (18874368)
    //  Ht_hi  bf16 [128][128][512] @ 37748736 (16777216)  M fp32 aliases (dead Ht)
    //  Ht_lo                   @ 54525952    (16777216)
    //  Wt_hi/lo                @ 71303168    (2x262144)
    //  GKt_hi/lo               @ 71827456    (2x884736)
    //  REC_hi/lo               @ 73596928    (2x32768)
    //  siga                    @ 73662464    (32)
    char* ws = (char*)d_ws;
    short* NG2_hi = (short*)(ws);
    short* NG2_lo = (short*)(ws + 18874368);
    short* Ht_hi  = (short*)(ws + 37748736);
    float* M      = (float*)(ws + 37748736);   // aliases Ht_hi (disjoint lifetime)
    short* Ht_lo  = (short*)(ws + 54525952);
    short* Wt_hi  = (short*)(ws + 71303168);
    short* Wt_lo  = (short*)(ws + 71565312);
    short* GKt_hi = (short*)(ws + 71827456);
    short* GKt_lo = (short*)(ws + 72712192);
    short* REC_hi = (short*)(ws + 73596928);
    short* REC_lo = (short*)(ws + 73629696);
    float* siga   = (float*)(ws + 73662464);

    k_prep<<<dim3(6401), 256, 0, stream>>>(w, gk, grk, alpha, init_state,
                                           Wt_hi, Wt_lo, GKt_hi, GKt_lo,
                                           REC_hi, REC_lo, NG2_hi, NG2_lo, siga);
    (void)hipMemcpyAsync(state, init_state, (size_t)8192 * 128 * sizeof(float),
                         hipMemcpyDeviceToDevice, stream);

    for (int step = 0; step < 3; ++step) {
        k_edge <<<dim3(64, 8),  256, 0, stream>>>(Wt_hi, Wt_lo, NG2_hi, NG2_lo,
                                                  bias, siga, Ht_hi, Ht_lo);
        k_neigh<<<dim3(4, 128), 256, 0, stream>>>(adj, Ht_hi, Ht_lo, NG2_hi, NG2_lo);
        k_gruin<<<dim3(3, 64),  256, 0, stream>>>(NG2_hi, NG2_lo, GKt_hi, GKt_lo,
                                                  gbias, M);
        k_hh   <<<dim3(256),    256, 0, stream>>>(M, REC_hi, REC_lo, state,
                                                  NG2_hi, NG2_lo);
    }
}